// Round 5
// baseline (456.386 us; speedup 1.0000x reference)
//
#include <hip/hip_runtime.h>
#include <hip/hip_bf16.h>
#include <hip/hip_fp8.h>
#include <stdint.h>

#define NN 16384
#define DD 512
#define MARGINV 2.0f
#define EPSV 1e-6f

#define BJ 32
#define JGROUPS 8               // grid = 128 bi x 8 bj = 1024 blocks (128 thr) = 4 blocks/CU
#define JRANGE (NN / JGROUPS)   // 2048
#define NTILES (JRANGE / BJ)    // 64
#define ROWQ 512                // fp8 row bytes
#define TILEB (BJ * ROWQ)       // 16384 B per tile buffer

#define KEYMASK  0xFFFFC000     // keep sign+exp+9 mantissa bits; low 14 = j (j<16384)
#define KEYINITF __builtin_bit_cast(float, 0x7F000000)   // big positive finite float
#define BIASV 640.0f            // > max sq_i: keys strictly positive, self provably rank 0

typedef __attribute__((ext_vector_type(4))) float f32x4;
typedef __attribute__((ext_vector_type(4))) int   i32x4;
typedef __attribute__((ext_vector_type(8))) int   i32x8;

#define UNIT_SCALE 0x7F   // E8M0 biased exponent 127 -> x1.0

// sorted-2 insert: m0 <= m1 kept, insert u (3 ops)
__device__ inline void kins2f(float u, float& m0, float& m1) {
  m1 = __builtin_amdgcn_fmed3f(m0, m1, u);
  m0 = fminf(m0, u);
}

// ---------------- Kernel 1: row sq-norms (fp32, +BIASV) + fp8 e4m3 quantize ----------------
extern "C" __global__ __launch_bounds__(256)
void prep_kernel(const float* __restrict__ x, unsigned char* __restrict__ xq,
                 float* __restrict__ sqb) {
  int row  = blockIdx.x * 4 + (threadIdx.x >> 6);
  int lane = threadIdx.x & 63;
  const float* xr = x + (size_t)row * DD + lane * 8;
  f32x4 a = *(const f32x4*)xr;
  f32x4 b = *(const f32x4*)(xr + 4);
  float s = a[0]*a[0]+a[1]*a[1]+a[2]*a[2]+a[3]*a[3]
          + b[0]*b[0]+b[1]*b[1]+b[2]*b[2]+b[3]*b[3];
  #pragma unroll
  for (int off = 1; off < 64; off <<= 1) s += __shfl_xor(s, off, 64);
  unsigned int w0 = (unsigned int)__builtin_amdgcn_cvt_pk_fp8_f32(a[0], a[1], 0, false);
  w0 = (unsigned int)__builtin_amdgcn_cvt_pk_fp8_f32(a[2], a[3], (int)w0, true);
  unsigned int w1 = (unsigned int)__builtin_amdgcn_cvt_pk_fp8_f32(b[0], b[1], 0, false);
  w1 = (unsigned int)__builtin_amdgcn_cvt_pk_fp8_f32(b[2], b[3], (int)w1, true);
  unsigned long long pk8 = ((unsigned long long)w1 << 32) | (unsigned long long)w0;
  *(unsigned long long*)(xq + (size_t)row * ROWQ + lane * 8) = pk8;
  if (lane == 0) sqb[row] = s + BIASV;
}

// ---------------- Kernel 2: fused MX-fp8 GEMM (X·X^T) + per-row packed top-2 -------------
// r1-exact per-wave structure (verified 152.7 us): 64 i-rows/wave, afr 4x4 resident
// (128 AGPR), single acc[4], epilogue after cluster 3. r2/r4 lesson: VGPR-side liveness
// must stay <= ~124 (unified file: 256/wave at 2 waves/SIMD, afr pins 128) -- no second
// acc array, no deferral. r3 lesson: never shrink the A-file / cap regs below 256.
// THIS round's single change: BARRIER DECOUPLING. 128-thr blocks (2 waves), 4
// independent blocks/CU (grid 1024, LDS 32KB/block = 128KB/CU). Same 8 waves/CU, but 4
// separate barrier domains -> when one block waits (lgkm, acc-wait, barrier drain),
// another block's waves feed the MFMA pipe. Zero per-wave register/instruction change.
// sqj via global load (r0<->r1 measured neutral), issued BEFORE staging so the in-order
// vmcnt return waits at vmcnt(8), not a drain. Top-2-EXCLUDING-SELF kept (verified;
// -16 VGPR headroom).
extern "C" __global__ __launch_bounds__(128, 2)
void knn_kernel(const unsigned char* __restrict__ xq, const float* __restrict__ sqb,
                int* __restrict__ pk) {
  __shared__ __align__(16) char lds[2 * TILEB];  // 32,768 B -> 4 blocks/CU
  const int tid  = threadIdx.x;
  const int wave = tid >> 6;                    // 0..1
  const int lane = tid & 63;
  const int quad = lane >> 4;
  const int r16  = lane & 15;
  const int bi   = blockIdx.x >> 3;             // 0..127
  const int bj   = blockIdx.x & 7;              // 0..7
  const int ibase = bi * 128 + wave * 64;       // 64 i-rows per wave
  const int jbase = bj * JRANGE;

  // A fragments: 4 sets x 4 k-chunks x 32 B = 128 regs (AGPR-resident on gfx950)
  i32x8 afr[4][4];
  #pragma unroll
  for (int s = 0; s < 4; ++s) {
    const unsigned char* ar = xq + (size_t)(ibase + s * 16 + r16) * ROWQ + quad * 32;
    #pragma unroll
    for (int c = 0; c < 4; ++c)
      afr[s][c] = *(const i32x8*)(ar + c * 128);
  }

  // packed top-2 (non-self) per (set s, reg r): q = s*4 + r
  float m0[16], m1[16];
  #pragma unroll
  for (int q = 0; q < 16; ++q) { m0[q] = m1[q] = KEYINITF; }

  // stage one 32-row B tile: 2 waves x 8 passes x (64 lanes x 16 B) = 16 KB
  auto stage = [&](int jt, int buf) {
    const int jrow0 = jbase + jt * BJ;
    #pragma unroll
    for (int p = 0; p < 8; ++p) {
      const int rr = wave * 16 + p * 2;                    // wave-uniform local row pair
      const int lr = rr + (lane >> 5);                     // per-lane local row
      const int u  = (lane & 31) ^ (lr & 7);               // FULL 3-bit swizzle
      const unsigned char* gsrc = xq + (size_t)(jrow0 + lr) * ROWQ + u * 16;
      char* ldst = lds + buf * TILEB + rr * ROWQ;          // wave-uniform base
      __builtin_amdgcn_global_load_lds((const __attribute__((address_space(1))) void*)gsrc,
                                       (__attribute__((address_space(3))) void*)ldst,
                                       16, 0, 0);
    }
  };

  const int sw = r16 & 7;

  // one MFMA cluster: 2 b128 LDS reads -> B frag -> 4 MFMAs (one per A-set)
  auto cluster = [&](const char* brow, int c, f32x4* acc) {
    const int g0 = c * 8 + quad * 2;
    i32x4 lo = *(const i32x4*)(brow + ((g0       ^ sw) * 16));
    i32x4 hi = *(const i32x4*)(brow + (((g0 + 1) ^ sw) * 16));
    i32x8 bf = i32x8{lo[0],lo[1],lo[2],lo[3],hi[0],hi[1],hi[2],hi[3]};
    __builtin_amdgcn_s_setprio(1);
    #pragma unroll
    for (int s = 0; s < 4; ++s)
      acc[s] = __builtin_amdgcn_mfma_scale_f32_16x16x128_f8f6f4(
                 afr[s][c], bf, acc[s], 0, 0, 0, UNIT_SCALE, 0, UNIT_SCALE);
    __builtin_amdgcn_s_setprio(0);
  };

  auto epilogue = [&](const f32x4* acc, float sqj, int j, bool diagt) {
    if (diagt) {
      #pragma unroll
      for (int s = 0; s < 4; ++s)
      #pragma unroll
      for (int r = 0; r < 4; ++r) {
        float v = fmaf(-2.0f, acc[s][r], sqj);
        int   b = (__builtin_bit_cast(int, v) & KEYMASK) | j;
        float u = __builtin_bit_cast(float, b);
        u = (j == (ibase + s * 16 + quad * 4 + r)) ? KEYINITF : u;   // exclude self
        kins2f(u, m0[s*4+r], m1[s*4+r]);
      }
    } else {
      #pragma unroll
      for (int s = 0; s < 4; ++s)
      #pragma unroll
      for (int r = 0; r < 4; ++r) {
        float v = fmaf(-2.0f, acc[s][r], sqj);
        int   b = (__builtin_bit_cast(int, v) & KEYMASK) | j;
        kins2f(__builtin_bit_cast(float, b), m0[s*4+r], m1[s*4+r]);
      }
    }
  };

  stage(0, 0);
  for (int jt = 0; jt < NTILES; ++jt) {
    __syncthreads();
    // sqj loads FIRST (oldest in vmcnt FIFO): epilogue waits at vmcnt(8), no drain
    const int   j0   = jbase + jt * BJ + r16;
    const int   j1   = j0 + 16;
    const float sqj0 = sqb[j0];
    const float sqj1 = sqb[j1];
    if (jt + 1 < NTILES) stage(jt + 1, (jt + 1) & 1);
    // diag tile iff this 32-j tile lies inside this block's 128-i range
    const bool diagt = (((jbase + jt * BJ) >> 7) == bi);
    const char* brow0 = lds + (jt & 1) * TILEB + r16 * ROWQ;          // jh0 B row
    const char* brow1 = brow0 + 16 * ROWQ;                            // jh1 B row

    f32x4 acc[4] = {{0.f,0.f,0.f,0.f},{0.f,0.f,0.f,0.f},
                    {0.f,0.f,0.f,0.f},{0.f,0.f,0.f,0.f}};
    cluster(brow0, 0, acc);
    cluster(brow0, 1, acc);
    cluster(brow0, 2, acc);
    cluster(brow0, 3, acc);
    epilogue(acc, sqj0, j0, diagt);

    #pragma unroll
    for (int s = 0; s < 4; ++s) acc[s] = f32x4{0.f,0.f,0.f,0.f};
    cluster(brow1, 0, acc);
    cluster(brow1, 1, acc);
    cluster(brow1, 2, acc);
    cluster(brow1, 3, acc);
    epilogue(acc, sqj1, j1, diagt);
  }

  // ------- in-register butterfly merge across r16 (masks 1,2,4,8 stay in-quad) -------
  #pragma unroll
  for (int m = 1; m <= 8; m <<= 1) {
    #pragma unroll
    for (int q = 0; q < 16; ++q) {
      float o0 = __shfl_xor(m0[q], m, 64);
      float o1 = __shfl_xor(m1[q], m, 64);
      kins2f(o0, m0[q], m1[q]);
      kins2f(o1, m0[q], m1[q]);
    }
  }

  // lane with r16 == q writes row q's merged packed top-2 (16 writers x 4 quads / wave)
  #pragma unroll
  for (int q = 0; q < 16; ++q) {
    if (r16 == q) {
      int s  = q >> 2, r = q & 3;
      int gi = ibase + s * 16 + quad * 4 + r;
      int ob = (gi * JGROUPS + bj) * 2;
      pk[ob + 0] = __builtin_bit_cast(int, m0[q]);
      pk[ob + 1] = __builtin_bit_cast(int, m1[q]);
    }
  }
}

// ---------------- Kernel 3: merge partials, fp32 norms, hinge -> per-block partial ----
// r3/r4-verified: parallel 16-lane pk merge + butterfly; 2048 blocks; no atomics.
extern "C" __global__ __launch_bounds__(256)
void finalize_kernel(const float* __restrict__ x, const float* __restrict__ pos,
                     const int* __restrict__ pk, float* __restrict__ partial) {
  __shared__ float wsum[4];
  int wave = threadIdx.x >> 6;
  int lane = threadIdx.x & 63;
  float acc = 0.f;
  #pragma unroll
  for (int rep = 0; rep < 2; ++rep) {
    int i = rep * 8192 + blockIdx.x * 4 + wave;
    // parallel top-2 merge of 16 packed keys: lanes 0..15 hold one key each
    float m0 = (lane < 16) ? __builtin_bit_cast(float, pk[i * 16 + lane]) : KEYINITF;
    float m1 = KEYINITF;
    #pragma unroll
    for (int m = 1; m <= 8; m <<= 1) {
      float o0 = __shfl_xor(m0, m, 64);
      float o1 = __shfl_xor(m1, m, 64);
      float t0 = fminf(m0, o0);
      m1 = fminf(fmaxf(m0, o0), fminf(m1, o1));   // 2nd smallest of sorted-pair union
      m0 = t0;
    }
    int neg = __shfl(__builtin_bit_cast(int, m1), 0, 64) & 0x3FFF;  // global rank-2
    const float* xr = x   + (size_t)i * DD + lane * 8;
    const float* pr = pos + (size_t)i * DD + lane * 8;
    const float* nr = x   + (size_t)neg * DD + lane * 8;
    f32x4 xa = *(const f32x4*)xr, xb4 = *(const f32x4*)(xr + 4);
    f32x4 pa = *(const f32x4*)pr, pb  = *(const f32x4*)(pr + 4);
    f32x4 na = *(const f32x4*)nr, nb  = *(const f32x4*)(nr + 4);
    float sap = 0.f, san = 0.f;
    #pragma unroll
    for (int k = 0; k < 4; ++k) {
      float d0 = xa[k]  - pa[k] + EPSV; sap = fmaf(d0, d0, sap);
      float d1 = xa[k]  - na[k] + EPSV; san = fmaf(d1, d1, san);
      float d2 = xb4[k] - pb[k] + EPSV; sap = fmaf(d2, d2, sap);
      float d3 = xb4[k] - nb[k] + EPSV; san = fmaf(d3, d3, san);
    }
    #pragma unroll
    for (int off = 1; off < 64; off <<= 1) {
      sap += __shfl_xor(sap, off, 64);
      san += __shfl_xor(san, off, 64);
    }
    if (lane == 0) {
      float l = sqrtf(sap) - sqrtf(san) + MARGINV;
      acc += (l > 0.f ? l : 0.f);
    }
  }
  if (lane == 0) wsum[wave] = acc;
  __syncthreads();
  if (threadIdx.x == 0) partial[blockIdx.x] = wsum[0] + wsum[1] + wsum[2] + wsum[3];
}

// ---------------- Kernel 4: reduce 2048 partials -> loss ----------------
extern "C" __global__ __launch_bounds__(256)
void reduce_kernel(const float* __restrict__ partial, float* __restrict__ out) {
  __shared__ float wsum[4];
  int tid = threadIdx.x;
  float s = 0.f;
  #pragma unroll
  for (int k = 0; k < 8; ++k) s += partial[tid + k * 256];
  #pragma unroll
  for (int off = 1; off < 64; off <<= 1) s += __shfl_xor(s, off, 64);
  if ((tid & 63) == 0) wsum[tid >> 6] = s;
  __syncthreads();
  if (tid == 0) out[0] = (wsum[0] + wsum[1] + wsum[2] + wsum[3]) * (1.0f / NN);
}

// ---------------- host ----------------
extern "C" void kernel_launch(void* const* d_in, const int* in_sizes, int n_in,
                              void* d_out, int out_size, void* d_ws, size_t ws_size,
                              hipStream_t stream) {
  const float* x   = (const float*)d_in[0];
  const float* pos = (const float*)d_in[1];
  char* ws = (char*)d_ws;
  unsigned char* xq   = (unsigned char*)ws;                                   // 8 MB
  float* sqb  = (float*)(ws + (size_t)NN * ROWQ);                             // 64 KB
  int*   pk   = (int*)  (ws + (size_t)NN * ROWQ + (size_t)NN * 4);            // 1 MB
  float* part = (float*)(ws + (size_t)NN * ROWQ + (size_t)NN * 4
                            + (size_t)NN * JGROUPS * 2 * 4);                  // 8 KB

  prep_kernel<<<NN / 4, 256, 0, stream>>>(x, xq, sqb);
  knn_kernel<<<(NN / 128) * JGROUPS, 128, 0, stream>>>(xq, sqb, pk);
  finalize_kernel<<<2048, 256, 0, stream>>>(x, pos, pk, part);
  reduce_kernel<<<1, 256, 0, stream>>>(part, (float*)d_out);
}

// Round 6
// 358.768 us; speedup vs baseline: 1.2721x; 1.2721x over previous
//
#include <hip/hip_runtime.h>
#include <hip/hip_bf16.h>
#include <hip/hip_fp8.h>
#include <stdint.h>

#define NN 16384
#define DD 512
#define MARGINV 2.0f
#define EPSV 1e-6f

#define BJ 32
#define JGROUPS 8               // grid = 64 bi x 8 bj = 512 = exactly 2 blocks/CU, zero tail
#define JRANGE (NN / JGROUPS)   // 2048
#define NTILES (JRANGE / BJ)    // 64
#define ROWQ 512                // fp8 row bytes
#define TILEB (BJ * ROWQ)       // 16384 B per tile buffer
#define SQOFF (2 * TILEB)       // sqb LDS offset (8 KB region)

#define KEYMASK  0xFFFFC000     // keep sign+exp+9 mantissa bits; low 14 = j (j<16384)
#define KEYINITF __builtin_bit_cast(float, 0x7F000000)   // big positive finite float
#define BIASV 640.0f            // > max sq_i: keys strictly positive, self provably rank 0

typedef __attribute__((ext_vector_type(4))) float f32x4;
typedef __attribute__((ext_vector_type(4))) int   i32x4;
typedef __attribute__((ext_vector_type(8))) int   i32x8;

#define UNIT_SCALE 0x7F   // E8M0 biased exponent 127 -> x1.0

// sorted-2 insert: m0 <= m1 kept, insert u (2 ops)
__device__ inline void kins2f(float u, float& m0, float& m1) {
  m1 = __builtin_amdgcn_fmed3f(m0, m1, u);
  m0 = fminf(m0, u);
}

// ---------------- Kernel 1: row sq-norms (fp32, +BIASV) + fp8 e4m3 quantize ----------------
extern "C" __global__ __launch_bounds__(256)
void prep_kernel(const float* __restrict__ x, unsigned char* __restrict__ xq,
                 float* __restrict__ sqb) {
  int row  = blockIdx.x * 4 + (threadIdx.x >> 6);
  int lane = threadIdx.x & 63;
  const float* xr = x + (size_t)row * DD + lane * 8;
  f32x4 a = *(const f32x4*)xr;
  f32x4 b = *(const f32x4*)(xr + 4);
  float s = a[0]*a[0]+a[1]*a[1]+a[2]*a[2]+a[3]*a[3]
          + b[0]*b[0]+b[1]*b[1]+b[2]*b[2]+b[3]*b[3];
  #pragma unroll
  for (int off = 1; off < 64; off <<= 1) s += __shfl_xor(s, off, 64);
  unsigned int w0 = (unsigned int)__builtin_amdgcn_cvt_pk_fp8_f32(a[0], a[1], 0, false);
  w0 = (unsigned int)__builtin_amdgcn_cvt_pk_fp8_f32(a[2], a[3], (int)w0, true);
  unsigned int w1 = (unsigned int)__builtin_amdgcn_cvt_pk_fp8_f32(b[0], b[1], 0, false);
  w1 = (unsigned int)__builtin_amdgcn_cvt_pk_fp8_f32(b[2], b[3], (int)w1, true);
  unsigned long long pk8 = ((unsigned long long)w1 << 32) | (unsigned long long)w0;
  *(unsigned long long*)(xq + (size_t)row * ROWQ + lane * 8) = pk8;
  if (lane == 0) sqb[row] = s + BIASV;
}

// ---------------- Kernel 2: fused MX-fp8 GEMM (X·X^T) + per-row packed top-2 -------------
// r1 VERBATIM structure (verified 152.7 us): 256 thr / 4 waves x 64 i-rows, afr 4x4
// resident, single acc[4] declared inside jh loop, FULLY INLINE hot loop (no lambdas
// with array params -- r4/r5 lesson: array-pointer params demote acc to scratch ->
// 27-31 MB scratch writes, MfmaUtil 15%). launch_bounds(256,2) (r3 lesson: never cap
// below 256 regs/wave). ONLY in-place change vs r1: top-2-EXCLUDING-SELF epilogue
// (r2-r5 correctness-verified): drop m2 (-16 VGPR), 4-op insert, self excluded by index
// compare on the 8 diagonal tiles per diagonal block only (wave-uniform branch).
extern "C" __global__ __launch_bounds__(256, 2)
void knn_kernel(const unsigned char* __restrict__ xq, const float* __restrict__ sqb,
                int* __restrict__ pk) {
  __shared__ __align__(16) char lds[2 * TILEB + 8192];  // 40,960 B
  const int tid  = threadIdx.x;
  const int wave = tid >> 6;
  const int lane = tid & 63;
  const int quad = lane >> 4;
  const int r16  = lane & 15;
  const int bi   = blockIdx.x >> 3;             // 0..63
  const int bj   = blockIdx.x & 7;              // 0..7
  const int ibase = bi * 256 + wave * 64;       // 64 i-rows per wave
  const int jbase = bj * JRANGE;

  // stage sqb[jbase .. jbase+2048) into LDS (8 KB): 2 passes x (4 waves x 64 lanes x 16 B)
  #pragma unroll
  for (int p = 0; p < 2; ++p) {
    const float* gs = sqb + jbase + p * 1024 + wave * 256 + lane * 4;
    char* ld = lds + SQOFF + p * 4096 + wave * 1024;    // wave-uniform base
    __builtin_amdgcn_global_load_lds((const __attribute__((address_space(1))) void*)gs,
                                     (__attribute__((address_space(3))) void*)ld,
                                     16, 0, 0);
  }

  // A fragments: 4 sets x 4 k-chunks x 32 B (v8i32). A[m=r16][k=chunk*128+quad*32+t]
  i32x8 afr[4][4];
  #pragma unroll
  for (int s = 0; s < 4; ++s) {
    const unsigned char* ar = xq + (size_t)(ibase + s * 16 + r16) * ROWQ + quad * 32;
    #pragma unroll
    for (int c = 0; c < 4; ++c)
      afr[s][c] = *(const i32x8*)(ar + c * 128);
  }

  // packed top-2 (non-self) per (set s, reg r): q = s*4 + r
  float m0[16], m1[16];
  #pragma unroll
  for (int q = 0; q < 16; ++q) { m0[q] = m1[q] = KEYINITF; }

  auto stage = [&](int jt, int buf) {
    const int jrow0 = jbase + jt * BJ;
    #pragma unroll
    for (int p = 0; p < 4; ++p) {
      const int rr = wave * 8 + p * 2;                     // wave-uniform local row pair
      const int lr = rr + (lane >> 5);                     // per-lane local row
      const int u  = (lane & 31) ^ (lr & 7);               // FULL 3-bit swizzle
      const unsigned char* gsrc = xq + (size_t)(jrow0 + lr) * ROWQ + u * 16;
      char* ldst = lds + buf * TILEB + rr * ROWQ;          // wave-uniform base
      __builtin_amdgcn_global_load_lds((const __attribute__((address_space(1))) void*)gsrc,
                                       (__attribute__((address_space(3))) void*)ldst,
                                       16, 0, 0);
    }
  };

  const int sw = r16 & 7;
  stage(0, 0);
  for (int jt = 0; jt < NTILES; ++jt) {
    __syncthreads();
    if (jt + 1 < NTILES) stage(jt + 1, (jt + 1) & 1);
    const bool diagt = ((bi >> 3) == bj) && ((jt >> 3) == (bi & 7));
    #pragma unroll
    for (int jh = 0; jh < 2; ++jh) {
      const char* brow = lds + (jt & 1) * TILEB + (jh * 16 + r16) * ROWQ;
      // sqj from LDS (broadcast across quads: conflict-free), lgkm counter not vmcnt
      const float sqj = *(const float*)(lds + SQOFF + ((jt * BJ + jh * 16 + r16) << 2));
      f32x4 acc[4] = {{0.f,0.f,0.f,0.f},{0.f,0.f,0.f,0.f},
                      {0.f,0.f,0.f,0.f},{0.f,0.f,0.f,0.f}};
      #pragma unroll
      for (int c = 0; c < 4; ++c) {
        const int g0 = c * 8 + quad * 2;
        i32x4 lo = *(const i32x4*)(brow + ((g0       ^ sw) * 16));
        i32x4 hi = *(const i32x4*)(brow + (((g0 + 1) ^ sw) * 16));
        i32x8 bf = i32x8{lo[0],lo[1],lo[2],lo[3],hi[0],hi[1],hi[2],hi[3]};
        __builtin_amdgcn_s_setprio(1);
        #pragma unroll
        for (int s = 0; s < 4; ++s)
          acc[s] = __builtin_amdgcn_mfma_scale_f32_16x16x128_f8f6f4(
                     afr[s][c], bf, acc[s], 0, 0, 0, UNIT_SCALE, 0, UNIT_SCALE);
        __builtin_amdgcn_s_setprio(0);
      }
      const int j = jbase + jt * BJ + jh * 16 + r16;
      if (diagt) {
        #pragma unroll
        for (int s = 0; s < 4; ++s)
        #pragma unroll
        for (int r = 0; r < 4; ++r) {
          float v = fmaf(-2.0f, acc[s][r], sqj);           // > 0 by BIASV construction
          int   b = (__builtin_bit_cast(int, v) & KEYMASK) | j;
          float u = __builtin_bit_cast(float, b);
          u = (j == (ibase + s * 16 + quad * 4 + r)) ? KEYINITF : u;   // exclude self
          kins2f(u, m0[s*4+r], m1[s*4+r]);
        }
      } else {
        #pragma unroll
        for (int s = 0; s < 4; ++s)
        #pragma unroll
        for (int r = 0; r < 4; ++r) {
          float v = fmaf(-2.0f, acc[s][r], sqj);
          int   b = (__builtin_bit_cast(int, v) & KEYMASK) | j;       // v_and_or_b32
          kins2f(__builtin_bit_cast(float, b), m0[s*4+r], m1[s*4+r]);
        }
      }
    }
  }

  // ------- in-register butterfly merge across r16 (masks 1,2,4,8 stay in-quad) -------
  #pragma unroll
  for (int m = 1; m <= 8; m <<= 1) {
    #pragma unroll
    for (int q = 0; q < 16; ++q) {
      float o0 = __shfl_xor(m0[q], m, 64);
      float o1 = __shfl_xor(m1[q], m, 64);
      kins2f(o0, m0[q], m1[q]);
      kins2f(o1, m0[q], m1[q]);
    }
  }

  // lane with r16 == q writes row q's merged packed top-2 (16 writers x 4 quads)
  #pragma unroll
  for (int q = 0; q < 16; ++q) {
    if (r16 == q) {
      int s  = q >> 2, r = q & 3;
      int gi = ibase + s * 16 + quad * 4 + r;
      int ob = (gi * JGROUPS + bj) * 2;
      pk[ob + 0] = __builtin_bit_cast(int, m0[q]);
      pk[ob + 1] = __builtin_bit_cast(int, m1[q]);
    }
  }
}

// ---------------- Kernel 3: merge partials, fp32 norms, hinge -> per-block partial ----
// r3/r4/r5-verified: parallel 16-lane pk merge + butterfly; 2048 blocks; no atomics.
extern "C" __global__ __launch_bounds__(256)
void finalize_kernel(const float* __restrict__ x, const float* __restrict__ pos,
                     const int* __restrict__ pk, float* __restrict__ partial) {
  __shared__ float wsum[4];
  int wave = threadIdx.x >> 6;
  int lane = threadIdx.x & 63;
  float acc = 0.f;
  #pragma unroll
  for (int rep = 0; rep < 2; ++rep) {
    int i = rep * 8192 + blockIdx.x * 4 + wave;
    // parallel top-2 merge of 16 packed keys: lanes 0..15 hold one key each
    float m0 = (lane < 16) ? __builtin_bit_cast(float, pk[i * 16 + lane]) : KEYINITF;
    float m1 = KEYINITF;
    #pragma unroll
    for (int m = 1; m <= 8; m <<= 1) {
      float o0 = __shfl_xor(m0, m, 64);
      float o1 = __shfl_xor(m1, m, 64);
      float t0 = fminf(m0, o0);
      m1 = fminf(fmaxf(m0, o0), fminf(m1, o1));   // 2nd smallest of sorted-pair union
      m0 = t0;
    }
    int neg = __shfl(__builtin_bit_cast(int, m1), 0, 64) & 0x3FFF;  // global rank-2
    const float* xr = x   + (size_t)i * DD + lane * 8;
    const float* pr = pos + (size_t)i * DD + lane * 8;
    const float* nr = x   + (size_t)neg * DD + lane * 8;
    f32x4 xa = *(const f32x4*)xr, xb4 = *(const f32x4*)(xr + 4);
    f32x4 pa = *(const f32x4*)pr, pb  = *(const f32x4*)(pr + 4);
    f32x4 na = *(const f32x4*)nr, nb  = *(const f32x4*)(nr + 4);
    float sap = 0.f, san = 0.f;
    #pragma unroll
    for (int k = 0; k < 4; ++k) {
      float d0 = xa[k]  - pa[k] + EPSV; sap = fmaf(d0, d0, sap);
      float d1 = xa[k]  - na[k] + EPSV; san = fmaf(d1, d1, san);
      float d2 = xb4[k] - pb[k] + EPSV; sap = fmaf(d2, d2, sap);
      float d3 = xb4[k] - nb[k] + EPSV; san = fmaf(d3, d3, san);
    }
    #pragma unroll
    for (int off = 1; off < 64; off <<= 1) {
      sap += __shfl_xor(sap, off, 64);
      san += __shfl_xor(san, off, 64);
    }
    if (lane == 0) {
      float l = sqrtf(sap) - sqrtf(san) + MARGINV;
      acc += (l > 0.f ? l : 0.f);
    }
  }
  if (lane == 0) wsum[wave] = acc;
  __syncthreads();
  if (threadIdx.x == 0) partial[blockIdx.x] = wsum[0] + wsum[1] + wsum[2] + wsum[3];
}

// ---------------- Kernel 4: reduce 2048 partials -> loss ----------------
extern "C" __global__ __launch_bounds__(256)
void reduce_kernel(const float* __restrict__ partial, float* __restrict__ out) {
  __shared__ float wsum[4];
  int tid = threadIdx.x;
  float s = 0.f;
  #pragma unroll
  for (int k = 0; k < 8; ++k) s += partial[tid + k * 256];
  #pragma unroll
  for (int off = 1; off < 64; off <<= 1) s += __shfl_xor(s, off, 64);
  if ((tid & 63) == 0) wsum[tid >> 6] = s;
  __syncthreads();
  if (tid == 0) out[0] = (wsum[0] + wsum[1] + wsum[2] + wsum[3]) * (1.0f / NN);
}

// ---------------- host ----------------
extern "C" void kernel_launch(void* const* d_in, const int* in_sizes, int n_in,
                              void* d_out, int out_size, void* d_ws, size_t ws_size,
                              hipStream_t stream) {
  const float* x   = (const float*)d_in[0];
  const float* pos = (const float*)d_in[1];
  char* ws = (char*)d_ws;
  unsigned char* xq   = (unsigned char*)ws;                                   // 8 MB
  float* sqb  = (float*)(ws + (size_t)NN * ROWQ);                             // 64 KB
  int*   pk   = (int*)  (ws + (size_t)NN * ROWQ + (size_t)NN * 4);            // 1 MB
  float* part = (float*)(ws + (size_t)NN * ROWQ + (size_t)NN * 4
                            + (size_t)NN * JGROUPS * 2 * 4);                  // 8 KB

  prep_kernel<<<NN / 4, 256, 0, stream>>>(x, xq, sqb);
  knn_kernel<<<(NN / 256) * JGROUPS, 256, 0, stream>>>(xq, sqb, pk);
  finalize_kernel<<<2048, 256, 0, stream>>>(x, pos, pk, part);
  reduce_kernel<<<1, 256, 0, stream>>>(part, (float*)d_out);
}

// Round 7
// 270.857 us; speedup vs baseline: 1.6850x; 1.3246x over previous
//
#include <hip/hip_runtime.h>
#include <hip/hip_bf16.h>
#include <hip/hip_fp8.h>
#include <stdint.h>

#define NN 16384
#define DD 512
#define MARGINV 2.0f
#define EPSV 1e-6f

#define BJ 32
#define JGROUPS 8               // grid = 64 bi x 8 bj = 512 = exactly 2 blocks/CU, zero tail
#define JRANGE (NN / JGROUPS)   // 2048
#define NTILES (JRANGE / BJ)    // 64
#define ROWQ 512                // fp8 row bytes
#define TILEB (BJ * ROWQ)       // 16384 B per tile buffer
#define SQOFF (2 * TILEB)       // sqb LDS offset (8 KB region)

#define KEYMASK  0xFFFFC000     // keep sign+exp+9 mantissa bits; low 14 = j (j<16384)
#define KEYINITF __builtin_bit_cast(float, 0x7F000000)   // big positive finite float
#define BIASV 640.0f            // > max sq_i: keys strictly positive, self provably rank 0

typedef __attribute__((ext_vector_type(4))) float f32x4;
typedef __attribute__((ext_vector_type(4))) int   i32x4;
typedef __attribute__((ext_vector_type(8))) int   i32x8;

#define UNIT_SCALE 0x7F   // E8M0 biased exponent 127 -> x1.0

// sorted-2 insert: m0 <= m1 kept, insert u (2 ops)
__device__ inline void kins2f(float u, float& m0, float& m1) {
  m1 = __builtin_amdgcn_fmed3f(m0, m1, u);
  m0 = fminf(m0, u);
}

// ---------------- Kernel 1: row sq-norms (fp32, +BIASV) + fp8 e4m3 quantize ----------------
extern "C" __global__ __launch_bounds__(256)
void prep_kernel(const float* __restrict__ x, unsigned char* __restrict__ xq,
                 float* __restrict__ sqb) {
  int row  = blockIdx.x * 4 + (threadIdx.x >> 6);
  int lane = threadIdx.x & 63;
  const float* xr = x + (size_t)row * DD + lane * 8;
  f32x4 a = *(const f32x4*)xr;
  f32x4 b = *(const f32x4*)(xr + 4);
  float s = a[0]*a[0]+a[1]*a[1]+a[2]*a[2]+a[3]*a[3]
          + b[0]*b[0]+b[1]*b[1]+b[2]*b[2]+b[3]*b[3];
  #pragma unroll
  for (int off = 1; off < 64; off <<= 1) s += __shfl_xor(s, off, 64);
  unsigned int w0 = (unsigned int)__builtin_amdgcn_cvt_pk_fp8_f32(a[0], a[1], 0, false);
  w0 = (unsigned int)__builtin_amdgcn_cvt_pk_fp8_f32(a[2], a[3], (int)w0, true);
  unsigned int w1 = (unsigned int)__builtin_amdgcn_cvt_pk_fp8_f32(b[0], b[1], 0, false);
  w1 = (unsigned int)__builtin_amdgcn_cvt_pk_fp8_f32(b[2], b[3], (int)w1, true);
  unsigned long long pk8 = ((unsigned long long)w1 << 32) | (unsigned long long)w0;
  *(unsigned long long*)(xq + (size_t)row * ROWQ + lane * 8) = pk8;
  if (lane == 0) sqb[row] = s + BIASV;
}

// ---------------- Kernel 2: fused MX-fp8 GEMM (X·X^T) + per-row packed top-2 -------------
// r1 structure (verified 152.7 us / 124 VGPR): 256 thr / 4 waves x 64 i-rows, afr 4x4
// resident (128 AGPR of the unified 256/wave), single acc[4] inside the jh loop, fully
// inline hot loop. Failure taxonomy now complete:
//   r2: cross-tile acc ping-pong -> liveness overflow -> spill.
//   r3: launch_bounds reg cap 64 -> A-file remat from global (10x FETCH).
//   r4/r5: array-param lambdas -> acc demoted to scratch.
//   r6: diag self-compare `j == ibase+s*16+quad*4+r` -> LICM hoists 16 loop-invariant
//       self-index constants live across the whole K-loop -> over 128 arch-VGPR -> spill.
// r7 fix: jrel = j - ibase - quad*4 (ONE register per jh); self iff jrel == s*16+r
// (RHS is an inline constant in v_cmp). Algebraically identical; kills the 16 hoisted
// regs. Everything else byte-identical to r6.
extern "C" __global__ __launch_bounds__(256, 2)
void knn_kernel(const unsigned char* __restrict__ xq, const float* __restrict__ sqb,
                int* __restrict__ pk) {
  __shared__ __align__(16) char lds[2 * TILEB + 8192];  // 40,960 B
  const int tid  = threadIdx.x;
  const int wave = tid >> 6;
  const int lane = tid & 63;
  const int quad = lane >> 4;
  const int r16  = lane & 15;
  const int bi   = blockIdx.x >> 3;             // 0..63
  const int bj   = blockIdx.x & 7;              // 0..7
  const int ibase = bi * 256 + wave * 64;       // 64 i-rows per wave
  const int jbase = bj * JRANGE;

  // stage sqb[jbase .. jbase+2048) into LDS (8 KB): 2 passes x (4 waves x 64 lanes x 16 B)
  #pragma unroll
  for (int p = 0; p < 2; ++p) {
    const float* gs = sqb + jbase + p * 1024 + wave * 256 + lane * 4;
    char* ld = lds + SQOFF + p * 4096 + wave * 1024;    // wave-uniform base
    __builtin_amdgcn_global_load_lds((const __attribute__((address_space(1))) void*)gs,
                                     (__attribute__((address_space(3))) void*)ld,
                                     16, 0, 0);
  }

  // A fragments: 4 sets x 4 k-chunks x 32 B (v8i32). A[m=r16][k=chunk*128+quad*32+t]
  i32x8 afr[4][4];
  #pragma unroll
  for (int s = 0; s < 4; ++s) {
    const unsigned char* ar = xq + (size_t)(ibase + s * 16 + r16) * ROWQ + quad * 32;
    #pragma unroll
    for (int c = 0; c < 4; ++c)
      afr[s][c] = *(const i32x8*)(ar + c * 128);
  }

  // packed top-2 (non-self) per (set s, reg r): q = s*4 + r
  float m0[16], m1[16];
  #pragma unroll
  for (int q = 0; q < 16; ++q) { m0[q] = m1[q] = KEYINITF; }

  auto stage = [&](int jt, int buf) {
    const int jrow0 = jbase + jt * BJ;
    #pragma unroll
    for (int p = 0; p < 4; ++p) {
      const int rr = wave * 8 + p * 2;                     // wave-uniform local row pair
      const int lr = rr + (lane >> 5);                     // per-lane local row
      const int u  = (lane & 31) ^ (lr & 7);               // FULL 3-bit swizzle
      const unsigned char* gsrc = xq + (size_t)(jrow0 + lr) * ROWQ + u * 16;
      char* ldst = lds + buf * TILEB + rr * ROWQ;          // wave-uniform base
      __builtin_amdgcn_global_load_lds((const __attribute__((address_space(1))) void*)gsrc,
                                       (__attribute__((address_space(3))) void*)ldst,
                                       16, 0, 0);
    }
  };

  const int sw = r16 & 7;
  stage(0, 0);
  for (int jt = 0; jt < NTILES; ++jt) {
    __syncthreads();
    if (jt + 1 < NTILES) stage(jt + 1, (jt + 1) & 1);
    const bool diagt = ((bi >> 3) == bj) && ((jt >> 3) == (bi & 7));
    #pragma unroll
    for (int jh = 0; jh < 2; ++jh) {
      const char* brow = lds + (jt & 1) * TILEB + (jh * 16 + r16) * ROWQ;
      // sqj from LDS (broadcast across quads: conflict-free), lgkm counter not vmcnt
      const float sqj = *(const float*)(lds + SQOFF + ((jt * BJ + jh * 16 + r16) << 2));
      f32x4 acc[4] = {{0.f,0.f,0.f,0.f},{0.f,0.f,0.f,0.f},
                      {0.f,0.f,0.f,0.f},{0.f,0.f,0.f,0.f}};
      #pragma unroll
      for (int c = 0; c < 4; ++c) {
        const int g0 = c * 8 + quad * 2;
        i32x4 lo = *(const i32x4*)(brow + ((g0       ^ sw) * 16));
        i32x4 hi = *(const i32x4*)(brow + (((g0 + 1) ^ sw) * 16));
        i32x8 bf = i32x8{lo[0],lo[1],lo[2],lo[3],hi[0],hi[1],hi[2],hi[3]};
        __builtin_amdgcn_s_setprio(1);
        #pragma unroll
        for (int s = 0; s < 4; ++s)
          acc[s] = __builtin_amdgcn_mfma_scale_f32_16x16x128_f8f6f4(
                     afr[s][c], bf, acc[s], 0, 0, 0, UNIT_SCALE, 0, UNIT_SCALE);
        __builtin_amdgcn_s_setprio(0);
      }
      const int j = jbase + jt * BJ + jh * 16 + r16;
      if (diagt) {
        // self iff j == ibase + s*16 + quad*4 + r  <=>  jrel == s*16 + r (inline const)
        const int jrel = j - ibase - quad * 4;             // ONE live register
        #pragma unroll
        for (int s = 0; s < 4; ++s)
        #pragma unroll
        for (int r = 0; r < 4; ++r) {
          float v = fmaf(-2.0f, acc[s][r], sqj);           // > 0 by BIASV construction
          int   b = (__builtin_bit_cast(int, v) & KEYMASK) | j;
          float u = __builtin_bit_cast(float, b);
          u = (jrel == (s * 16 + r)) ? KEYINITF : u;       // exclude self
          kins2f(u, m0[s*4+r], m1[s*4+r]);
        }
      } else {
        #pragma unroll
        for (int s = 0; s < 4; ++s)
        #pragma unroll
        for (int r = 0; r < 4; ++r) {
          float v = fmaf(-2.0f, acc[s][r], sqj);
          int   b = (__builtin_bit_cast(int, v) & KEYMASK) | j;       // v_and_or_b32
          kins2f(__builtin_bit_cast(float, b), m0[s*4+r], m1[s*4+r]);
        }
      }
    }
  }

  // ------- in-register butterfly merge across r16 (masks 1,2,4,8 stay in-quad) -------
  #pragma unroll
  for (int m = 1; m <= 8; m <<= 1) {
    #pragma unroll
    for (int q = 0; q < 16; ++q) {
      float o0 = __shfl_xor(m0[q], m, 64);
      float o1 = __shfl_xor(m1[q], m, 64);
      kins2f(o0, m0[q], m1[q]);
      kins2f(o1, m0[q], m1[q]);
    }
  }

  // lane with r16 == q writes row q's merged packed top-2 (16 writers x 4 quads)
  #pragma unroll
  for (int q = 0; q < 16; ++q) {
    if (r16 == q) {
      int s  = q >> 2, r = q & 3;
      int gi = ibase + s * 16 + quad * 4 + r;
      int ob = (gi * JGROUPS + bj) * 2;
      pk[ob + 0] = __builtin_bit_cast(int, m0[q]);
      pk[ob + 1] = __builtin_bit_cast(int, m1[q]);
    }
  }
}

// ---------------- Kernel 3: merge partials, fp32 norms, hinge -> per-block partial ----
// r3-r6 verified: parallel 16-lane pk merge + butterfly; 2048 blocks; no atomics.
extern "C" __global__ __launch_bounds__(256)
void finalize_kernel(const float* __restrict__ x, const float* __restrict__ pos,
                     const int* __restrict__ pk, float* __restrict__ partial) {
  __shared__ float wsum[4];
  int wave = threadIdx.x >> 6;
  int lane = threadIdx.x & 63;
  float acc = 0.f;
  #pragma unroll
  for (int rep = 0; rep < 2; ++rep) {
    int i = rep * 8192 + blockIdx.x * 4 + wave;
    // parallel top-2 merge of 16 packed keys: lanes 0..15 hold one key each
    float m0 = (lane < 16) ? __builtin_bit_cast(float, pk[i * 16 + lane]) : KEYINITF;
    float m1 = KEYINITF;
    #pragma unroll
    for (int m = 1; m <= 8; m <<= 1) {
      float o0 = __shfl_xor(m0, m, 64);
      float o1 = __shfl_xor(m1, m, 64);
      float t0 = fminf(m0, o0);
      m1 = fminf(fmaxf(m0, o0), fminf(m1, o1));   // 2nd smallest of sorted-pair union
      m0 = t0;
    }
    int neg = __shfl(__builtin_bit_cast(int, m1), 0, 64) & 0x3FFF;  // global rank-2
    const float* xr = x   + (size_t)i * DD + lane * 8;
    const float* pr = pos + (size_t)i * DD + lane * 8;
    const float* nr = x   + (size_t)neg * DD + lane * 8;
    f32x4 xa = *(const f32x4*)xr, xb4 = *(const f32x4*)(xr + 4);
    f32x4 pa = *(const f32x4*)pr, pb  = *(const f32x4*)(pr + 4);
    f32x4 na = *(const f32x4*)nr, nb  = *(const f32x4*)(nr + 4);
    float sap = 0.f, san = 0.f;
    #pragma unroll
    for (int k = 0; k < 4; ++k) {
      float d0 = xa[k]  - pa[k] + EPSV; sap = fmaf(d0, d0, sap);
      float d1 = xa[k]  - na[k] + EPSV; san = fmaf(d1, d1, san);
      float d2 = xb4[k] - pb[k] + EPSV; sap = fmaf(d2, d2, sap);
      float d3 = xb4[k] - nb[k] + EPSV; san = fmaf(d3, d3, san);
    }
    #pragma unroll
    for (int off = 1; off < 64; off <<= 1) {
      sap += __shfl_xor(sap, off, 64);
      san += __shfl_xor(san, off, 64);
    }
    if (lane == 0) {
      float l = sqrtf(sap) - sqrtf(san) + MARGINV;
      acc += (l > 0.f ? l : 0.f);
    }
  }
  if (lane == 0) wsum[wave] = acc;
  __syncthreads();
  if (threadIdx.x == 0) partial[blockIdx.x] = wsum[0] + wsum[1] + wsum[2] + wsum[3];
}

// ---------------- Kernel 4: reduce 2048 partials -> loss ----------------
extern "C" __global__ __launch_bounds__(256)
void reduce_kernel(const float* __restrict__ partial, float* __restrict__ out) {
  __shared__ float wsum[4];
  int tid = threadIdx.x;
  float s = 0.f;
  #pragma unroll
  for (int k = 0; k < 8; ++k) s += partial[tid + k * 256];
  #pragma unroll
  for (int off = 1; off < 64; off <<= 1) s += __shfl_xor(s, off, 64);
  if ((tid & 63) == 0) wsum[tid >> 6] = s;
  __syncthreads();
  if (tid == 0) out[0] = (wsum[0] + wsum[1] + wsum[2] + wsum[3]) * (1.0f / NN);
}

// ---------------- host ----------------
extern "C" void kernel_launch(void* const* d_in, const int* in_sizes, int n_in,
                              void* d_out, int out_size, void* d_ws, size_t ws_size,
                              hipStream_t stream) {
  const float* x   = (const float*)d_in[0];
  const float* pos = (const float*)d_in[1];
  char* ws = (char*)d_ws;
  unsigned char* xq   = (unsigned char*)ws;                                   // 8 MB
  float* sqb  = (float*)(ws + (size_t)NN * ROWQ);                             // 64 KB
  int*   pk   = (int*)  (ws + (size_t)NN * ROWQ + (size_t)NN * 4);            // 1 MB
  float* part = (float*)(ws + (size_t)NN * ROWQ + (size_t)NN * 4
                            + (size_t)NN * JGROUPS * 2 * 4);                  // 8 KB

  prep_kernel<<<NN / 4, 256, 0, stream>>>(x, xq, sqb);
  knn_kernel<<<(NN / 256) * JGROUPS, 256, 0, stream>>>(xq, sqb, pk);
  finalize_kernel<<<2048, 256, 0, stream>>>(x, pos, pk, part);
  reduce_kernel<<<1, 256, 0, stream>>>(part, (float*)d_out);
}

// Round 8
// 228.046 us; speedup vs baseline: 2.0013x; 1.1877x over previous
//
#include <hip/hip_runtime.h>
#include <hip/hip_bf16.h>
#include <hip/hip_fp8.h>
#include <stdint.h>

#define NN 16384
#define DD 512
#define MARGINV 2.0f
#define EPSV 1e-6f

#define BJ 32
#define JGROUPS 8               // grid = 64 bi x 8 bj = 512 = exactly 2 blocks/CU, zero tail
#define JRANGE (NN / JGROUPS)   // 2048
#define NTILES (JRANGE / BJ)    // 64
#define ROWQ 512                // fp8 row bytes
#define TILEB (BJ * ROWQ)       // 16384 B per tile buffer
#define SQOFF (2 * TILEB)       // sqb LDS offset (8 KB region)

#define KEYMASK  0xFFFFC000     // keep sign+exp+9 mantissa bits; low 14 = j (j<16384)
#define KEYINITF __builtin_bit_cast(float, 0x7F000000)   // big positive finite float
#define BIASV 640.0f            // > max sq_i: keys strictly positive, self provably rank 0

typedef __attribute__((ext_vector_type(4))) float f32x4;
typedef __attribute__((ext_vector_type(4))) int   i32x4;
typedef __attribute__((ext_vector_type(8))) int   i32x8;

#define UNIT_SCALE 0x7F   // E8M0 biased exponent 127 -> x1.0

// sorted-2 insert: m0 <= m1 kept, insert u (2 ops)
__device__ inline void kins2f(float u, float& m0, float& m1) {
  m1 = __builtin_amdgcn_fmed3f(m0, m1, u);
  m0 = fminf(m0, u);
}

// ---------------- Kernel 1: row sq-norms (fp32, +BIASV) + fp8 e4m3 quantize ----------------
extern "C" __global__ __launch_bounds__(256)
void prep_kernel(const float* __restrict__ x, unsigned char* __restrict__ xq,
                 float* __restrict__ sqb) {
  int row  = blockIdx.x * 4 + (threadIdx.x >> 6);
  int lane = threadIdx.x & 63;
  const float* xr = x + (size_t)row * DD + lane * 8;
  f32x4 a = *(const f32x4*)xr;
  f32x4 b = *(const f32x4*)(xr + 4);
  float s = a[0]*a[0]+a[1]*a[1]+a[2]*a[2]+a[3]*a[3]
          + b[0]*b[0]+b[1]*b[1]+b[2]*b[2]+b[3]*b[3];
  #pragma unroll
  for (int off = 1; off < 64; off <<= 1) s += __shfl_xor(s, off, 64);
  unsigned int w0 = (unsigned int)__builtin_amdgcn_cvt_pk_fp8_f32(a[0], a[1], 0, false);
  w0 = (unsigned int)__builtin_amdgcn_cvt_pk_fp8_f32(a[2], a[3], (int)w0, true);
  unsigned int w1 = (unsigned int)__builtin_amdgcn_cvt_pk_fp8_f32(b[0], b[1], 0, false);
  w1 = (unsigned int)__builtin_amdgcn_cvt_pk_fp8_f32(b[2], b[3], (int)w1, true);
  unsigned long long pk8 = ((unsigned long long)w1 << 32) | (unsigned long long)w0;
  *(unsigned long long*)(xq + (size_t)row * ROWQ + lane * 8) = pk8;
  if (lane == 0) sqb[row] = s + BIASV;
}

// ---------------- Kernel 2: fused MX-fp8 GEMM (X·X^T) + per-row packed top-2 -------------
// r1 hot loop BYTE-FAITHFUL (verified 152.7 us / 124 VGPR, no spill): 256 thr / 4 waves
// x 64 i-rows, afr 4x4 resident, acc[4] inside jh loop, fully inline, NO setprio (r1
// had none; m190 measured it ~0-to-negative on lockstep structures). Only deltas:
//  (a) top-2 instead of top-3: m2 dropped (-16 regs vs r1's verified fit).
//  (b) UNCONDITIONAL self-exclusion: `jrel == s*16+r` is automatically false on every
//      non-diagonal tile (j outside block's i-range), so NO diagt branch at all --
//      r7 lesson: the dual-body wave-uniform branch widened peak liveness -> spill.
//      Cost: 1 v_cmp + 1 v_cndmask per element vs inline consts; jrel = 1 reg per jh.
// Spill guards for this round: VGPR_Count must NOT read 128; WRITE_SIZE ~5 MB.
extern "C" __global__ __launch_bounds__(256, 2)
void knn_kernel(const unsigned char* __restrict__ xq, const float* __restrict__ sqb,
                int* __restrict__ pk) {
  __shared__ __align__(16) char lds[2 * TILEB + 8192];  // 40,960 B
  const int tid  = threadIdx.x;
  const int wave = tid >> 6;
  const int lane = tid & 63;
  const int quad = lane >> 4;
  const int r16  = lane & 15;
  const int bi   = blockIdx.x >> 3;             // 0..63
  const int bj   = blockIdx.x & 7;              // 0..7
  const int ibase = bi * 256 + wave * 64;       // 64 i-rows per wave
  const int jbase = bj * JRANGE;

  // stage sqb[jbase .. jbase+2048) into LDS (8 KB): 2 passes x (4 waves x 64 lanes x 16 B)
  #pragma unroll
  for (int p = 0; p < 2; ++p) {
    const float* gs = sqb + jbase + p * 1024 + wave * 256 + lane * 4;
    char* ld = lds + SQOFF + p * 4096 + wave * 1024;    // wave-uniform base
    __builtin_amdgcn_global_load_lds((const __attribute__((address_space(1))) void*)gs,
                                     (__attribute__((address_space(3))) void*)ld,
                                     16, 0, 0);
  }

  // A fragments: 4 sets x 4 k-chunks x 32 B (v8i32). A[m=r16][k=chunk*128+quad*32+t]
  i32x8 afr[4][4];
  #pragma unroll
  for (int s = 0; s < 4; ++s) {
    const unsigned char* ar = xq + (size_t)(ibase + s * 16 + r16) * ROWQ + quad * 32;
    #pragma unroll
    for (int c = 0; c < 4; ++c)
      afr[s][c] = *(const i32x8*)(ar + c * 128);
  }

  // packed top-2 (non-self) per (set s, reg r): q = s*4 + r
  float m0[16], m1[16];
  #pragma unroll
  for (int q = 0; q < 16; ++q) { m0[q] = m1[q] = KEYINITF; }

  auto stage = [&](int jt, int buf) {
    const int jrow0 = jbase + jt * BJ;
    #pragma unroll
    for (int p = 0; p < 4; ++p) {
      const int rr = wave * 8 + p * 2;                     // wave-uniform local row pair
      const int lr = rr + (lane >> 5);                     // per-lane local row
      const int u  = (lane & 31) ^ (lr & 7);               // FULL 3-bit swizzle
      const unsigned char* gsrc = xq + (size_t)(jrow0 + lr) * ROWQ + u * 16;
      char* ldst = lds + buf * TILEB + rr * ROWQ;          // wave-uniform base
      __builtin_amdgcn_global_load_lds((const __attribute__((address_space(1))) void*)gsrc,
                                       (__attribute__((address_space(3))) void*)ldst,
                                       16, 0, 0);
    }
  };

  const int sw = r16 & 7;
  stage(0, 0);
  for (int jt = 0; jt < NTILES; ++jt) {
    __syncthreads();
    if (jt + 1 < NTILES) stage(jt + 1, (jt + 1) & 1);
    #pragma unroll
    for (int jh = 0; jh < 2; ++jh) {
      const char* brow = lds + (jt & 1) * TILEB + (jh * 16 + r16) * ROWQ;
      // sqj from LDS (broadcast across quads: conflict-free), lgkm counter not vmcnt
      const float sqj = *(const float*)(lds + SQOFF + ((jt * BJ + jh * 16 + r16) << 2));
      f32x4 acc[4] = {{0.f,0.f,0.f,0.f},{0.f,0.f,0.f,0.f},
                      {0.f,0.f,0.f,0.f},{0.f,0.f,0.f,0.f}};
      #pragma unroll
      for (int c = 0; c < 4; ++c) {
        const int g0 = c * 8 + quad * 2;
        i32x4 lo = *(const i32x4*)(brow + ((g0       ^ sw) * 16));
        i32x4 hi = *(const i32x4*)(brow + (((g0 + 1) ^ sw) * 16));
        i32x8 bf = i32x8{lo[0],lo[1],lo[2],lo[3],hi[0],hi[1],hi[2],hi[3]};
        #pragma unroll
        for (int s = 0; s < 4; ++s)
          acc[s] = __builtin_amdgcn_mfma_scale_f32_16x16x128_f8f6f4(
                     afr[s][c], bf, acc[s], 0, 0, 0, UNIT_SCALE, 0, UNIT_SCALE);
      }
      const int j = jbase + jt * BJ + jh * 16 + r16;
      // self iff j == ibase + s*16 + quad*4 + r  <=>  jrel == s*16 + r (inline consts);
      // automatically false off-diagonal -- no branch needed.
      const int jrel = j - ibase - quad * 4;
      #pragma unroll
      for (int s = 0; s < 4; ++s)
      #pragma unroll
      for (int r = 0; r < 4; ++r) {
        float v = fmaf(-2.0f, acc[s][r], sqj);             // > 0 by BIASV construction
        int   b = (__builtin_bit_cast(int, v) & KEYMASK) | j;   // v_and_or_b32
        float u = __builtin_bit_cast(float, b);
        u = (jrel == (s * 16 + r)) ? KEYINITF : u;         // exclude self (cndmask)
        kins2f(u, m0[s*4+r], m1[s*4+r]);
      }
    }
  }

  // ------- in-register butterfly merge across r16 (masks 1,2,4,8 stay in-quad) -------
  #pragma unroll
  for (int m = 1; m <= 8; m <<= 1) {
    #pragma unroll
    for (int q = 0; q < 16; ++q) {
      float o0 = __shfl_xor(m0[q], m, 64);
      float o1 = __shfl_xor(m1[q], m, 64);
      kins2f(o0, m0[q], m1[q]);
      kins2f(o1, m0[q], m1[q]);
    }
  }

  // lane with r16 == q writes row q's merged packed top-2 (16 writers x 4 quads)
  #pragma unroll
  for (int q = 0; q < 16; ++q) {
    if (r16 == q) {
      int s  = q >> 2, r = q & 3;
      int gi = ibase + s * 16 + quad * 4 + r;
      int ob = (gi * JGROUPS + bj) * 2;
      pk[ob + 0] = __builtin_bit_cast(int, m0[q]);
      pk[ob + 1] = __builtin_bit_cast(int, m1[q]);
    }
  }
}

// ---------------- Kernel 3: merge partials, fp32 norms, hinge -> per-block partial ----
// r3-r7 verified: parallel 16-lane pk merge + butterfly; 2048 blocks; no atomics.
extern "C" __global__ __launch_bounds__(256)
void finalize_kernel(const float* __restrict__ x, const float* __restrict__ pos,
                     const int* __restrict__ pk, float* __restrict__ partial) {
  __shared__ float wsum[4];
  int wave = threadIdx.x >> 6;
  int lane = threadIdx.x & 63;
  float acc = 0.f;
  #pragma unroll
  for (int rep = 0; rep < 2; ++rep) {
    int i = rep * 8192 + blockIdx.x * 4 + wave;
    // parallel top-2 merge of 16 packed keys: lanes 0..15 hold one key each
    float m0 = (lane < 16) ? __builtin_bit_cast(float, pk[i * 16 + lane]) : KEYINITF;
    float m1 = KEYINITF;
    #pragma unroll
    for (int m = 1; m <= 8; m <<= 1) {
      float o0 = __shfl_xor(m0, m, 64);
      float o1 = __shfl_xor(m1, m, 64);
      float t0 = fminf(m0, o0);
      m1 = fminf(fmaxf(m0, o0), fminf(m1, o1));   // 2nd smallest of sorted-pair union
      m0 = t0;
    }
    int neg = __shfl(__builtin_bit_cast(int, m1), 0, 64) & 0x3FFF;  // global rank-2
    const float* xr = x   + (size_t)i * DD + lane * 8;
    const float* pr = pos + (size_t)i * DD + lane * 8;
    const float* nr = x   + (size_t)neg * DD + lane * 8;
    f32x4 xa = *(const f32x4*)xr, xb4 = *(const f32x4*)(xr + 4);
    f32x4 pa = *(const f32x4*)pr, pb  = *(const f32x4*)(pr + 4);
    f32x4 na = *(const f32x4*)nr, nb  = *(const f32x4*)(nr + 4);
    float sap = 0.f, san = 0.f;
    #pragma unroll
    for (int k = 0; k < 4; ++k) {
      float d0 = xa[k]  - pa[k] + EPSV; sap = fmaf(d0, d0, sap);
      float d1 = xa[k]  - na[k] + EPSV; san = fmaf(d1, d1, san);
      float d2 = xb4[k] - pb[k] + EPSV; sap = fmaf(d2, d2, sap);
      float d3 = xb4[k] - nb[k] + EPSV; san = fmaf(d3, d3, san);
    }
    #pragma unroll
    for (int off = 1; off < 64; off <<= 1) {
      sap += __shfl_xor(sap, off, 64);
      san += __shfl_xor(san, off, 64);
    }
    if (lane == 0) {
      float l = sqrtf(sap) - sqrtf(san) + MARGINV;
      acc += (l > 0.f ? l : 0.f);
    }
  }
  if (lane == 0) wsum[wave] = acc;
  __syncthreads();
  if (threadIdx.x == 0) partial[blockIdx.x] = wsum[0] + wsum[1] + wsum[2] + wsum[3];
}

// ---------------- Kernel 4: reduce 2048 partials -> loss ----------------
extern "C" __global__ __launch_bounds__(256)
void reduce_kernel(const float* __restrict__ partial, float* __restrict__ out) {
  __shared__ float wsum[4];
  int tid = threadIdx.x;
  float s = 0.f;
  #pragma unroll
  for (int k = 0; k < 8; ++k) s += partial[tid + k * 256];
  #pragma unroll
  for (int off = 1; off < 64; off <<= 1) s += __shfl_xor(s, off, 64);
  if ((tid & 63) == 0) wsum[tid >> 6] = s;
  __syncthreads();
  if (tid == 0) out[0] = (wsum[0] + wsum[1] + wsum[2] + wsum[3]) * (1.0f / NN);
}

// ---------------- host ----------------
extern "C" void kernel_launch(void* const* d_in, const int* in_sizes, int n_in,
                              void* d_out, int out_size, void* d_ws, size_t ws_size,
                              hipStream_t stream) {
  const float* x   = (const float*)d_in[0];
  const float* pos = (const float*)d_in[1];
  char* ws = (char*)d_ws;
  unsigned char* xq   = (unsigned char*)ws;                                   // 8 MB
  float* sqb  = (float*)(ws + (size_t)NN * ROWQ);                             // 64 KB
  int*   pk   = (int*)  (ws + (size_t)NN * ROWQ + (size_t)NN * 4);            // 1 MB
  float* part = (float*)(ws + (size_t)NN * ROWQ + (size_t)NN * 4
                            + (size_t)NN * JGROUPS * 2 * 4);                  // 8 KB

  prep_kernel<<<NN / 4, 256, 0, stream>>>(x, xq, sqb);
  knn_kernel<<<(NN / 256) * JGROUPS, 256, 0, stream>>>(xq, sqb, pk);
  finalize_kernel<<<2048, 256, 0, stream>>>(x, pos, pk, part);
  reduce_kernel<<<1, 256, 0, stream>>>(part, (float*)d_out);
}